// Round 1
// baseline (561.862 us; speedup 1.0000x reference)
//
#include <hip/hip_runtime.h>
#include <hip/hip_bf16.h>
#include <stdint.h>

#define DEVI __device__ __forceinline__

typedef __attribute__((ext_vector_type(8))) short bf16x8;
typedef __attribute__((ext_vector_type(4))) float f32x4;

DEVI short f2bf(float f) {
  unsigned int u = __builtin_bit_cast(unsigned int, f);
  u = (u + 0x7fffu + ((u >> 16) & 1u)) >> 16;
  return (short)u;
}

DEVI void gload_lds16(const void* g, void* lds) {
  __builtin_amdgcn_global_load_lds(
      (const __attribute__((address_space(1))) unsigned int*)g,
      (__attribute__((address_space(3))) unsigned int*)lds, 16, 0, 0);
}

// ---------------- converts ----------------

// fp32 -> bf16, 4 elems/thread, exact multiple
__global__ __launch_bounds__(256) void cvt_kernel(const float* __restrict__ in,
                                                  short* __restrict__ out) {
  int idx = (blockIdx.x * 256 + threadIdx.x) * 4;
  float4 v = *reinterpret_cast<const float4*>(in + idx);
  out[idx + 0] = f2bf(v.x);
  out[idx + 1] = f2bf(v.y);
  out[idx + 2] = f2bf(v.z);
  out[idx + 3] = f2bf(v.w);
}

// W [K=1024][N] fp32 -> W^T [N][1024] bf16
__global__ __launch_bounds__(256) void cvtT_kernel(const float* __restrict__ in,
                                                   short* __restrict__ out, int N) {
  int i = blockIdx.x * 256 + threadIdx.x;  // over N*K
  int n = i >> 10, k = i & 1023;
  out[i] = f2bf(in[k * N + n]);
}

// ---------------- GEMM core (A[M,K] bf16 row-major, Bt[N,K] bf16 row-major) ----------------
// 128x128 tile, 4 waves (2x2), each wave 64x64 = 4x4 fragments of 16x16x32.

DEVI void gemm_core(const short* __restrict__ A, const short* __restrict__ Bt, int K,
                    int m0, int n0, short* sA, short* sB, f32x4 acc[4][4]) {
  const int tid = threadIdx.x;
  const int lane = tid & 63;
  const int wave = tid >> 6;
  const int wr = wave >> 1, wc = wave & 1;
  const int lr = lane & 15, kg = lane >> 4;

#pragma unroll
  for (int i = 0; i < 4; ++i)
#pragma unroll
    for (int j = 0; j < 4; ++j) {
      f32x4 z = {0.f, 0.f, 0.f, 0.f};
      acc[i][j] = z;
    }

  const int mrow = tid & 127;        // staging row (0..127)
  const int g0 = tid >> 7;           // 0..1
  const short* Abase = A + (long)(m0 + mrow) * K;
  const short* Bbase = Bt + (long)(n0 + mrow) * K;

  for (int k0 = 0; k0 < K; k0 += 32) {
    // stage A-tile: LDS layout [g=k/8][m][8], linear chunk j = g*128+m = tid (+256)
    gload_lds16(Abase + k0 + g0 * 8, (char*)sA + tid * 16);
    gload_lds16(Abase + k0 + (2 + g0) * 8, (char*)sA + tid * 16 + 4096);
    gload_lds16(Bbase + k0 + g0 * 8, (char*)sB + tid * 16);
    gload_lds16(Bbase + k0 + (2 + g0) * 8, (char*)sB + tid * 16 + 4096);
    __syncthreads();  // vmcnt(0) drained before barrier -> tiles visible

    bf16x8 af[4], bfm[4];
#pragma unroll
    for (int mi = 0; mi < 4; ++mi)
      af[mi] = *(const bf16x8*)(sA + ((kg * 128) + wr * 64 + mi * 16 + lr) * 8);
#pragma unroll
    for (int ni = 0; ni < 4; ++ni)
      bfm[ni] = *(const bf16x8*)(sB + ((kg * 128) + wc * 64 + ni * 16 + lr) * 8);
#pragma unroll
    for (int mi = 0; mi < 4; ++mi)
#pragma unroll
      for (int ni = 0; ni < 4; ++ni)
        acc[mi][ni] = __builtin_amdgcn_mfma_f32_16x16x32_bf16(af[mi], bfm[ni], acc[mi][ni], 0, 0, 0);
    __syncthreads();
  }
}

// ---------------- QKV GEMM ----------------
// C[m][n] = x[m][:] . W_attn[:][n] + b_attn[n];  m=b*1024+t, n in [0,3072)
// writes Q,K as [bh][t][64] bf16, V transposed as [bh][d][1024] bf16

__global__ __launch_bounds__(256) void qkv_gemm_kernel(const short* __restrict__ xb,
                                                       const short* __restrict__ WaT,
                                                       const float* __restrict__ b_attn,
                                                       short* __restrict__ Qb,
                                                       short* __restrict__ Kb,
                                                       short* __restrict__ Vt) {
  __shared__ short sA[4096], sB[4096];
  const int bidm = blockIdx.x & 127, bidn = blockIdx.x >> 7;  // 128 x 24
  const int m0 = bidm * 128, n0 = bidn * 128;
  f32x4 acc[4][4];
  gemm_core(xb, WaT, 1024, m0, n0, sA, sB, acc);

  const int lane = threadIdx.x & 63, wave = threadIdx.x >> 6;
  const int wr = wave >> 1, wc = wave & 1, lr = lane & 15, lq = lane >> 4;
#pragma unroll
  for (int mi = 0; mi < 4; ++mi)
#pragma unroll
    for (int ni = 0; ni < 4; ++ni) {
      const int n = n0 + wc * 64 + ni * 16 + lr;
      const float bias = b_attn[n];
      const int part = n >> 10, c = n & 1023, h = c >> 6, d = c & 63;
#pragma unroll
      for (int r = 0; r < 4; ++r) {
        const int m = m0 + wr * 64 + mi * 16 + lq * 4 + r;
        const int b = m >> 10, t = m & 1023;
        const int bh = b * 16 + h;
        const short bv = f2bf(acc[mi][ni][r] + bias);
        if (part == 0)
          Qb[((long)bh * 1024 + t) * 64 + d] = bv;
        else if (part == 1)
          Kb[((long)bh * 1024 + t) * 64 + d] = bv;
        else
          Vt[((long)bh * 64 + d) * 1024 + t] = bv;
      }
    }
}

// ---------------- flash attention ----------------
// block = (bh, qt): 64 q-rows, 4 waves each own 16 rows; KV tiles of 64.

__global__ __launch_bounds__(256) void attn_kernel(const short* __restrict__ Qb,
                                                   const short* __restrict__ Kb,
                                                   const short* __restrict__ Vt,
                                                   short* __restrict__ Yb) {
  __shared__ short sK[4096], sV[4096];
  __shared__ short sP[4][1024];  // per-wave 16x64 P tile

  const int bid = blockIdx.x;      // bh*16 + qt
  const int qt = bid & 15;
  const int bh = bid >> 4;
  const int b = bh >> 4, h = bh & 15;
  const int tid = threadIdx.x, lane = tid & 63, wave = tid >> 6;
  const int lr = lane & 15, lq = lane >> 4;
  const int q0 = qt * 64;

  // Q fragments in registers: row (A-layout) = lane&15
  const short* qrow = Qb + ((long)bh * 1024 + q0 + wave * 16 + lr) * 64;
  bf16x8 qf[2];
  qf[0] = *(const bf16x8*)(qrow + lq * 8);
  qf[1] = *(const bf16x8*)(qrow + 32 + lq * 8);

  f32x4 yacc[4];
#pragma unroll
  for (int i = 0; i < 4; ++i) {
    f32x4 z = {0.f, 0.f, 0.f, 0.f};
    yacc[i] = z;
  }
  float mrow[4], lsum[4];
#pragma unroll
  for (int r = 0; r < 4; ++r) { mrow[r] = -1e30f; lsum[r] = 0.f; }

  const short* Kbh = Kb + (long)bh * 1024 * 64;
  const short* Vbh = Vt + (long)bh * 64 * 1024;
  short* myP = &sP[wave][0];

  for (int kt = 0; kt <= qt; ++kt) {
    // stage K tile: LDS [g=d/8][t][8]; chunk j = g*64+t ; j = tid, tid+256
    gload_lds16(Kbh + ((long)(kt * 64 + (tid & 63))) * 64 + (tid >> 6) * 8, (char*)sK + tid * 16);
    gload_lds16(Kbh + ((long)(kt * 64 + (tid & 63))) * 64 + (4 + (tid >> 6)) * 8, (char*)sK + tid * 16 + 4096);
    // stage V tile: LDS [g=t/8][d][8]; source Vt[d][kt*64 + g*8 ..]
    gload_lds16(Vbh + (long)(tid & 63) * 1024 + kt * 64 + (tid >> 6) * 8, (char*)sV + tid * 16);
    gload_lds16(Vbh + (long)(tid & 63) * 1024 + kt * 64 + (4 + (tid >> 6)) * 8, (char*)sV + tid * 16 + 4096);
    __syncthreads();

    // S = Q K^T  (rows: 16 q-rows of this wave; cols: 64 kv)
    f32x4 s[4];
#pragma unroll
    for (int i = 0; i < 4; ++i) {
      f32x4 z = {0.f, 0.f, 0.f, 0.f};
      s[i] = z;
    }
#pragma unroll
    for (int kk = 0; kk < 2; ++kk) {
#pragma unroll
      for (int ni = 0; ni < 4; ++ni) {
        bf16x8 kf = *(const bf16x8*)(sK + ((kk * 4 + lq) * 64 + ni * 16 + lr) * 8);
        s[ni] = __builtin_amdgcn_mfma_f32_16x16x32_bf16(qf[kk], kf, s[ni], 0, 0, 0);
      }
    }

    const bool diag = (kt == qt);
#pragma unroll
    for (int ni = 0; ni < 4; ++ni)
#pragma unroll
      for (int r = 0; r < 4; ++r) {
        float v = s[ni][r] * 0.125f;
        if (diag) {
          int tkl = ni * 16 + lr;
          int tql = lq * 4 + r;  // same 64-block, wave-local rows compare within tile
          // global: tq = q0 + wave*16 + tql ; tk = q0 + tkl  -> mask if tkl > wave*16+tql
          if (tkl > wave * 16 + tql) v = -1e30f;
        }
        s[ni][r] = v;
      }

    // online softmax (rows r -> 4 rows per lane, groups of 16 lanes share a row)
    float alpha[4], rsum[4];
#pragma unroll
    for (int r = 0; r < 4; ++r) {
      float mx = fmaxf(fmaxf(s[0][r], s[1][r]), fmaxf(s[2][r], s[3][r]));
      mx = fmaxf(mx, __shfl_xor(mx, 1));
      mx = fmaxf(mx, __shfl_xor(mx, 2));
      mx = fmaxf(mx, __shfl_xor(mx, 4));
      mx = fmaxf(mx, __shfl_xor(mx, 8));
      float mnew = fmaxf(mrow[r], mx);
      alpha[r] = __expf(mrow[r] - mnew);
      mrow[r] = mnew;
      rsum[r] = 0.f;
    }

    // P = exp(s-m) -> bf16 into per-wave LDS (XOR-swizzled), D-layout -> A-layout transpose
#pragma unroll
    for (int ni = 0; ni < 4; ++ni)
#pragma unroll
      for (int r = 0; r < 4; ++r) {
        float p = __expf(s[ni][r] - mrow[r]);
        rsum[r] += p;
        int row = lq * 4 + r, col = ni * 16 + lr;
        int off = (row * 128 + col * 2) ^ ((row & 7) << 4);
        *(short*)((char*)myP + off) = f2bf(p);
      }
#pragma unroll
    for (int r = 0; r < 4; ++r) {
      float sm = rsum[r];
      sm += __shfl_xor(sm, 1);
      sm += __shfl_xor(sm, 2);
      sm += __shfl_xor(sm, 4);
      sm += __shfl_xor(sm, 8);
      lsum[r] = lsum[r] * alpha[r] + sm;
    }
#pragma unroll
    for (int ni = 0; ni < 4; ++ni)
#pragma unroll
      for (int r = 0; r < 4; ++r) yacc[ni][r] *= alpha[r];

    // PV: A-frag from P (row = lane&15), B-frag from V^T tile
#pragma unroll
    for (int kk = 0; kk < 2; ++kk) {
      int off = (lr * 128 + kk * 64 + lq * 16) ^ ((lr & 7) << 4);
      bf16x8 pf = *(const bf16x8*)((char*)myP + off);
#pragma unroll
      for (int ni = 0; ni < 4; ++ni) {
        bf16x8 vf = *(const bf16x8*)(sV + ((kk * 4 + lq) * 64 + ni * 16 + lr) * 8);
        yacc[ni] = __builtin_amdgcn_mfma_f32_16x16x32_bf16(pf, vf, yacc[ni], 0, 0, 0);
      }
    }
    __syncthreads();
  }

  // epilogue: normalize + write Y as [b][t][h*64+d] bf16
#pragma unroll
  for (int ni = 0; ni < 4; ++ni)
#pragma unroll
    for (int r = 0; r < 4; ++r) {
      int t = q0 + wave * 16 + lq * 4 + r;
      int d = ni * 16 + lr;
      float v = yacc[ni][r] / lsum[r];
      Yb[((long)b * 1024 + t) * 1024 + h * 64 + d] = f2bf(v);
    }
}

// ---------------- output projection GEMM ----------------

__global__ __launch_bounds__(256) void proj_gemm_kernel(const short* __restrict__ Yb,
                                                        const short* __restrict__ WpT,
                                                        const float* __restrict__ b_proj,
                                                        float* __restrict__ out) {
  __shared__ short sA[4096], sB[4096];
  const int bidm = blockIdx.x & 127, bidn = blockIdx.x >> 7;  // 128 x 8
  const int m0 = bidm * 128, n0 = bidn * 128;
  f32x4 acc[4][4];
  gemm_core(Yb, WpT, 1024, m0, n0, sA, sB, acc);

  const int lane = threadIdx.x & 63, wave = threadIdx.x >> 6;
  const int wr = wave >> 1, wc = wave & 1, lr = lane & 15, lq = lane >> 4;
#pragma unroll
  for (int mi = 0; mi < 4; ++mi)
#pragma unroll
    for (int ni = 0; ni < 4; ++ni) {
      const int n = n0 + wc * 64 + ni * 16 + lr;
      const float bias = b_proj[n];
#pragma unroll
      for (int r = 0; r < 4; ++r) {
        const int m = m0 + wr * 64 + mi * 16 + lq * 4 + r;
        out[(long)m * 1024 + n] = acc[mi][ni][r] + bias;
      }
    }
}

// ---------------- launcher ----------------

extern "C" void kernel_launch(void* const* d_in, const int* in_sizes, int n_in,
                              void* d_out, int out_size, void* d_ws, size_t ws_size,
                              hipStream_t stream) {
  const float* x = (const float*)d_in[0];
  const float* W_attn = (const float*)d_in[1];
  const float* b_attn = (const float*)d_in[2];
  const float* W_proj = (const float*)d_in[3];
  const float* b_proj = (const float*)d_in[4];
  float* out = (float*)d_out;

  char* ws = (char*)d_ws;
  short* xb = (short*)(ws + 0);            // 16384x1024 bf16 : 32 MB
  short* WaT = (short*)(ws + 33554432);    // 3072x1024 bf16  : 6 MB
  short* WpT = (short*)(ws + 39845888);    // 1024x1024 bf16  : 2 MB
  short* Qb = (short*)(ws + 41943040);     // [256][1024][64] : 32 MB
  short* Kb = (short*)(ws + 75497472);     // [256][1024][64] : 32 MB
  short* Vt = (short*)(ws + 109051904);    // [256][64][1024] : 32 MB
  short* Yb = (short*)(ws + 142606336);    // 16384x1024 bf16 : 32 MB

  cvt_kernel<<<16384, 256, 0, stream>>>(x, xb);
  cvtT_kernel<<<12288, 256, 0, stream>>>(W_attn, WaT, 3072);
  cvtT_kernel<<<4096, 256, 0, stream>>>(W_proj, WpT, 1024);
  qkv_gemm_kernel<<<3072, 256, 0, stream>>>(xb, WaT, b_attn, Qb, Kb, Vt);
  attn_kernel<<<4096, 256, 0, stream>>>(Qb, Kb, Vt, Yb);
  proj_gemm_kernel<<<1024, 256, 0, stream>>>(Yb, WpT, b_proj, out);
}

// Round 2
// 435.031 us; speedup vs baseline: 1.2915x; 1.2915x over previous
//
#include <hip/hip_runtime.h>
#include <hip/hip_bf16.h>
#include <stdint.h>

#define DEVI __device__ __forceinline__

typedef __attribute__((ext_vector_type(8))) short bf16x8;
typedef __attribute__((ext_vector_type(4))) float f32x4;

DEVI short f2bf(float f) {
  unsigned int u = __builtin_bit_cast(unsigned int, f);
  u = (u + 0x7fffu + ((u >> 16) & 1u)) >> 16;
  return (short)u;
}

DEVI void gload_lds16(const void* g, void* lds) {
  __builtin_amdgcn_global_load_lds(
      (const __attribute__((address_space(1))) unsigned int*)g,
      (__attribute__((address_space(3))) unsigned int*)lds, 16, 0, 0);
}

// ---------------- converts ----------------

__global__ __launch_bounds__(256) void cvt_kernel(const float* __restrict__ in,
                                                  short* __restrict__ out) {
  int idx = (blockIdx.x * 256 + threadIdx.x) * 4;
  float4 v = *reinterpret_cast<const float4*>(in + idx);
  out[idx + 0] = f2bf(v.x);
  out[idx + 1] = f2bf(v.y);
  out[idx + 2] = f2bf(v.z);
  out[idx + 3] = f2bf(v.w);
}

// W [K=1024][N] fp32 -> W^T [N][1024] bf16, LDS-tiled 64x64 transpose (coalesced both sides)
__global__ __launch_bounds__(256) void cvtT_kernel(const float* __restrict__ in,
                                                   short* __restrict__ out, int N) {
  __shared__ short tile[64][65];
  const int tid = threadIdx.x;
  const int nblk = N >> 6;
  const int nt = blockIdx.x % nblk, kt = blockIdx.x / nblk;
  const int c = tid & 63, r4 = tid >> 6;
#pragma unroll
  for (int r = 0; r < 16; ++r) {
    const int kl = r * 4 + r4;
    tile[kl][c] = f2bf(in[(long)(kt * 64 + kl) * N + nt * 64 + c]);
  }
  __syncthreads();
#pragma unroll
  for (int r = 0; r < 16; ++r) {
    const int nl = r * 4 + r4;
    out[((long)(nt * 64 + nl) << 10) + kt * 64 + c] = tile[c][nl];
  }
}

// ---------------- 256x256 GEMM core, BK=64, 8 waves (2x4), 4-phase pipelined ----------------
// A [M][1024] bf16 row-major; Bt [N][1024] bf16 row-major. K hardcoded 1024.
// LDS: 2 buffers x (A 256x64 + B 256x64) bf16 = 128 KiB.
// Swizzle (rule #21): linear gload_lds dest + inverse-XOR global source; readers XOR
// byte col with (row&7)<<4 -> 2-way max bank aliasing on ds_read_b128.

DEVI void gemm256_core(const short* __restrict__ A, const short* __restrict__ Bt,
                       int m0, int n0, short (*sA)[16384], short (*sB)[16384],
                       f32x4 (&acc)[8][4]) {
  const int tid = threadIdx.x;
  const int lane = tid & 63, wave = tid >> 6;
  const int wr = wave >> 2, wc = wave & 3;
  const int lr = lane & 15, kg = lane >> 4;

#pragma unroll
  for (int i = 0; i < 8; ++i)
#pragma unroll
    for (int j = 0; j < 4; ++j) {
      f32x4 z = {0.f, 0.f, 0.f, 0.f};
      acc[i][j] = z;
    }

  // staging source pointers (pre-swizzled column so linear LDS + swizzled read agree)
  const int srow = tid >> 3;
  const int scol = ((((tid & 7) << 4)) ^ ((srow & 7) << 4)) >> 1;  // element offset in [0,64)
  const short* pA = A + (long)(m0 + srow) * 1024 + scol;
  const short* pB = Bt + (long)(n0 + srow) * 1024 + scol;

  // prologue: stage K-tile 0 into buf 0
#pragma unroll
  for (int r = 0; r < 4; ++r) {
    gload_lds16(pA + (long)r * 65536, (char*)sA[0] + r * 8192 + tid * 16);
    gload_lds16(pB + (long)r * 65536, (char*)sB[0] + r * 8192 + tid * 16);
  }
  __syncthreads();

  // swizzled byte-column offsets for fragment reads (kk = 0,1)
  const int cswz0 = ((kg << 4)) ^ ((lr & 7) << 4);
  const int cswz1 = (64 + (kg << 4)) ^ ((lr & 7) << 4);

  int cur = 0;
  for (int kt = 0; kt < 16; ++kt) {
    const short* sa = sA[cur];
    const short* sb = sB[cur];
    const short* Asrc = pA + (kt + 1) * 64;
    const short* Bsrc = pB + (kt + 1) * 64;
    char* sAn = (char*)sA[cur ^ 1];
    char* sBn = (char*)sB[cur ^ 1];
    const bool notlast = (kt < 15);
    bf16x8 af[4][2], bfr[2][2];

#pragma unroll
    for (int ph = 0; ph < 4; ++ph) {
      const int mh = ph >> 1;
      const int nh = (ph == 1 || ph == 2) ? 1 : 0;
      // register subtile loads (A reused across n-halves, B across m-halves)
      if (ph == 0 || ph == 2) {
#pragma unroll
        for (int mi = 0; mi < 4; ++mi) {
          const int row = wr * 128 + mh * 64 + mi * 16 + lr;
          af[mi][0] = *(const bf16x8*)((const char*)sa + row * 128 + cswz0);
          af[mi][1] = *(const bf16x8*)((const char*)sa + row * 128 + cswz1);
        }
      }
      if (ph != 2) {
#pragma unroll
        for (int ni = 0; ni < 2; ++ni) {
          const int row = wc * 64 + nh * 32 + ni * 16 + lr;
          bfr[ni][0] = *(const bf16x8*)((const char*)sb + row * 128 + cswz0);
          bfr[ni][1] = *(const bf16x8*)((const char*)sb + row * 128 + cswz1);
        }
      }
      // stage one round of next K-tile into the other buffer (stays in flight)
      if (notlast) {
        gload_lds16(Asrc + (long)ph * 65536, sAn + ph * 8192 + tid * 16);
        gload_lds16(Bsrc + (long)ph * 65536, sBn + ph * 8192 + tid * 16);
      }
      __builtin_amdgcn_s_barrier();
      __builtin_amdgcn_s_setprio(1);
#pragma unroll
      for (int mi = 0; mi < 4; ++mi)
#pragma unroll
        for (int ni = 0; ni < 2; ++ni) {
          f32x4* a = &acc[mh * 4 + mi][nh * 2 + ni];
          *a = __builtin_amdgcn_mfma_f32_16x16x32_bf16(af[mi][0], bfr[ni][0], *a, 0, 0, 0);
          *a = __builtin_amdgcn_mfma_f32_16x16x32_bf16(af[mi][1], bfr[ni][1], *a, 0, 0, 0);
        }
      __builtin_amdgcn_s_setprio(0);
    }
    if (notlast) __syncthreads();  // drains vmcnt: next tile fully in LDS for all waves
    cur ^= 1;
  }
}

// ---------------- QKV GEMM ----------------
// C[m][n] = x[m][:] . W_attn[:][n] + b_attn[n];  m = b*1024+t, n in [0,3072)
// writes Q,K as [bh][t][64] bf16, V transposed as [bh][d][1024] bf16

__global__ __launch_bounds__(512, 2) void qkv_gemm_kernel(const short* __restrict__ xb,
                                                          const short* __restrict__ WaT,
                                                          const float* __restrict__ b_attn,
                                                          short* __restrict__ Qb,
                                                          short* __restrict__ Kb,
                                                          short* __restrict__ Vt) {
  __shared__ short sA[2][16384], sB[2][16384];
  const int bidm = blockIdx.x & 63, bidn = blockIdx.x >> 6;  // 64 x 12
  const int m0 = bidm << 8, n0 = bidn << 8;
  f32x4 acc[8][4];
  gemm256_core(xb, WaT, m0, n0, sA, sB, acc);

  const int lane = threadIdx.x & 63, wave = threadIdx.x >> 6;
  const int wr = wave >> 2, wc = wave & 3, lr = lane & 15, kg = lane >> 4;
#pragma unroll
  for (int ni = 0; ni < 4; ++ni) {
    const int n = n0 + wc * 64 + ni * 16 + lr;
    const float bias = b_attn[n];
    const int part = n >> 10, c = n & 1023, h = c >> 6, d = c & 63;
#pragma unroll
    for (int mi = 0; mi < 8; ++mi)
#pragma unroll
      for (int r = 0; r < 4; ++r) {
        const int m = m0 + wr * 128 + mi * 16 + kg * 4 + r;
        const int b = m >> 10, t = m & 1023;
        const int bh = b * 16 + h;
        const short bv = f2bf(acc[mi][ni][r] + bias);
        if (part == 0)
          Qb[((long)bh * 1024 + t) * 64 + d] = bv;
        else if (part == 1)
          Kb[((long)bh * 1024 + t) * 64 + d] = bv;
        else
          Vt[((long)bh * 64 + d) * 1024 + t] = bv;
      }
  }
}

// ---------------- flash attention (unchanged from passing round) ----------------

__global__ __launch_bounds__(256) void attn_kernel(const short* __restrict__ Qb,
                                                   const short* __restrict__ Kb,
                                                   const short* __restrict__ Vt,
                                                   short* __restrict__ Yb) {
  __shared__ short sK[4096], sV[4096];
  __shared__ short sP[4][1024];

  const int bid = blockIdx.x;
  const int qt = bid & 15;
  const int bh = bid >> 4;
  const int b = bh >> 4, h = bh & 15;
  const int tid = threadIdx.x, lane = tid & 63, wave = tid >> 6;
  const int lr = lane & 15, lq = lane >> 4;
  const int q0 = qt * 64;

  const short* qrow = Qb + ((long)bh * 1024 + q0 + wave * 16 + lr) * 64;
  bf16x8 qf[2];
  qf[0] = *(const bf16x8*)(qrow + lq * 8);
  qf[1] = *(const bf16x8*)(qrow + 32 + lq * 8);

  f32x4 yacc[4];
#pragma unroll
  for (int i = 0; i < 4; ++i) {
    f32x4 z = {0.f, 0.f, 0.f, 0.f};
    yacc[i] = z;
  }
  float mrow[4], lsum[4];
#pragma unroll
  for (int r = 0; r < 4; ++r) { mrow[r] = -1e30f; lsum[r] = 0.f; }

  const short* Kbh = Kb + (long)bh * 1024 * 64;
  const short* Vbh = Vt + (long)bh * 64 * 1024;
  short* myP = &sP[wave][0];

  for (int kt = 0; kt <= qt; ++kt) {
    gload_lds16(Kbh + ((long)(kt * 64 + (tid & 63))) * 64 + (tid >> 6) * 8, (char*)sK + tid * 16);
    gload_lds16(Kbh + ((long)(kt * 64 + (tid & 63))) * 64 + (4 + (tid >> 6)) * 8, (char*)sK + tid * 16 + 4096);
    gload_lds16(Vbh + (long)(tid & 63) * 1024 + kt * 64 + (tid >> 6) * 8, (char*)sV + tid * 16);
    gload_lds16(Vbh + (long)(tid & 63) * 1024 + kt * 64 + (4 + (tid >> 6)) * 8, (char*)sV + tid * 16 + 4096);
    __syncthreads();

    f32x4 s[4];
#pragma unroll
    for (int i = 0; i < 4; ++i) {
      f32x4 z = {0.f, 0.f, 0.f, 0.f};
      s[i] = z;
    }
#pragma unroll
    for (int kk = 0; kk < 2; ++kk) {
#pragma unroll
      for (int ni = 0; ni < 4; ++ni) {
        bf16x8 kf = *(const bf16x8*)(sK + ((kk * 4 + lq) * 64 + ni * 16 + lr) * 8);
        s[ni] = __builtin_amdgcn_mfma_f32_16x16x32_bf16(qf[kk], kf, s[ni], 0, 0, 0);
      }
    }

    const bool diag = (kt == qt);
#pragma unroll
    for (int ni = 0; ni < 4; ++ni)
#pragma unroll
      for (int r = 0; r < 4; ++r) {
        float v = s[ni][r] * 0.125f;
        if (diag) {
          int tkl = ni * 16 + lr;
          int tql = lq * 4 + r;
          if (tkl > wave * 16 + tql) v = -1e30f;
        }
        s[ni][r] = v;
      }

    float alpha[4], rsum[4];
#pragma unroll
    for (int r = 0; r < 4; ++r) {
      float mx = fmaxf(fmaxf(s[0][r], s[1][r]), fmaxf(s[2][r], s[3][r]));
      mx = fmaxf(mx, __shfl_xor(mx, 1));
      mx = fmaxf(mx, __shfl_xor(mx, 2));
      mx = fmaxf(mx, __shfl_xor(mx, 4));
      mx = fmaxf(mx, __shfl_xor(mx, 8));
      float mnew = fmaxf(mrow[r], mx);
      alpha[r] = __expf(mrow[r] - mnew);
      mrow[r] = mnew;
      rsum[r] = 0.f;
    }

#pragma unroll
    for (int ni = 0; ni < 4; ++ni)
#pragma unroll
      for (int r = 0; r < 4; ++r) {
        float p = __expf(s[ni][r] - mrow[r]);
        rsum[r] += p;
        int row = lq * 4 + r, col = ni * 16 + lr;
        int off = (row * 128 + col * 2) ^ ((row & 7) << 4);
        *(short*)((char*)myP + off) = f2bf(p);
      }
#pragma unroll
    for (int r = 0; r < 4; ++r) {
      float sm = rsum[r];
      sm += __shfl_xor(sm, 1);
      sm += __shfl_xor(sm, 2);
      sm += __shfl_xor(sm, 4);
      sm += __shfl_xor(sm, 8);
      lsum[r] = lsum[r] * alpha[r] + sm;
    }
#pragma unroll
    for (int ni = 0; ni < 4; ++ni)
#pragma unroll
      for (int r = 0; r < 4; ++r) yacc[ni][r] *= alpha[r];

#pragma unroll
    for (int kk = 0; kk < 2; ++kk) {
      int off = (lr * 128 + kk * 64 + lq * 16) ^ ((lr & 7) << 4);
      bf16x8 pf = *(const bf16x8*)((char*)myP + off);
#pragma unroll
      for (int ni = 0; ni < 4; ++ni) {
        bf16x8 vf = *(const bf16x8*)(sV + ((kk * 4 + lq) * 64 + ni * 16 + lr) * 8);
        yacc[ni] = __builtin_amdgcn_mfma_f32_16x16x32_bf16(pf, vf, yacc[ni], 0, 0, 0);
      }
    }
    __syncthreads();
  }

#pragma unroll
  for (int ni = 0; ni < 4; ++ni)
#pragma unroll
    for (int r = 0; r < 4; ++r) {
      int t = q0 + wave * 16 + lq * 4 + r;
      int d = ni * 16 + lr;
      float v = yacc[ni][r] / lsum[r];
      Yb[((long)b * 1024 + t) * 1024 + h * 64 + d] = f2bf(v);
    }
}

// ---------------- output projection GEMM ----------------

__global__ __launch_bounds__(512, 2) void proj_gemm_kernel(const short* __restrict__ Yb,
                                                           const short* __restrict__ WpT,
                                                           const float* __restrict__ b_proj,
                                                           float* __restrict__ out) {
  __shared__ short sA[2][16384], sB[2][16384];
  const int bidm = blockIdx.x & 63, bidn = blockIdx.x >> 6;  // 64 x 4
  const int m0 = bidm << 8, n0 = bidn << 8;
  f32x4 acc[8][4];
  gemm256_core(Yb, WpT, m0, n0, sA, sB, acc);

  const int lane = threadIdx.x & 63, wave = threadIdx.x >> 6;
  const int wr = wave >> 2, wc = wave & 3, lr = lane & 15, kg = lane >> 4;
#pragma unroll
  for (int ni = 0; ni < 4; ++ni) {
    const int n = n0 + wc * 64 + ni * 16 + lr;
    const float bias = b_proj[n];
#pragma unroll
    for (int mi = 0; mi < 8; ++mi)
#pragma unroll
      for (int r = 0; r < 4; ++r) {
        const int m = m0 + wr * 128 + mi * 16 + kg * 4 + r;
        out[(long)m * 1024 + n] = acc[mi][ni][r] + bias;
      }
  }
}

// ---------------- launcher ----------------

extern "C" void kernel_launch(void* const* d_in, const int* in_sizes, int n_in,
                              void* d_out, int out_size, void* d_ws, size_t ws_size,
                              hipStream_t stream) {
  const float* x = (const float*)d_in[0];
  const float* W_attn = (const float*)d_in[1];
  const float* b_attn = (const float*)d_in[2];
  const float* W_proj = (const float*)d_in[3];
  const float* b_proj = (const float*)d_in[4];
  float* out = (float*)d_out;

  char* ws = (char*)d_ws;
  short* xb = (short*)(ws + 0);            // 16384x1024 bf16 : 32 MB
  short* WaT = (short*)(ws + 33554432);    // 3072x1024 bf16  : 6 MB
  short* WpT = (short*)(ws + 39845888);    // 1024x1024 bf16  : 2 MB
  short* Qb = (short*)(ws + 41943040);     // [256][1024][64] : 32 MB
  short* Kb = (short*)(ws + 75497472);     // [256][1024][64] : 32 MB
  short* Vt = (short*)(ws + 109051904);    // [256][64][1024] : 32 MB
  short* Yb = (short*)(ws + 142606336);    // 16384x1024 bf16 : 32 MB

  cvt_kernel<<<16384, 256, 0, stream>>>(x, xb);
  cvtT_kernel<<<768, 256, 0, stream>>>(W_attn, WaT, 3072);
  cvtT_kernel<<<256, 256, 0, stream>>>(W_proj, WpT, 1024);
  qkv_gemm_kernel<<<768, 512, 0, stream>>>(xb, WaT, b_attn, Qb, Kb, Vt);
  attn_kernel<<<4096, 256, 0, stream>>>(Qb, Kb, Vt, Yb);
  proj_gemm_kernel<<<256, 512, 0, stream>>>(Yb, WpT, b_proj, out);
}

// Round 3
// 362.778 us; speedup vs baseline: 1.5488x; 1.1992x over previous
//
#include <hip/hip_runtime.h>
#include <hip/hip_bf16.h>
#include <stdint.h>

#define DEVI __device__ __forceinline__

typedef __attribute__((ext_vector_type(8))) short bf16x8;
typedef __attribute__((ext_vector_type(4))) float f32x4;

DEVI short f2bf(float f) {
  unsigned int u = __builtin_bit_cast(unsigned int, f);
  u = (u + 0x7fffu + ((u >> 16) & 1u)) >> 16;
  return (short)u;
}

DEVI void gload_lds16(const void* g, void* lds) {
  __builtin_amdgcn_global_load_lds(
      (const __attribute__((address_space(1))) unsigned int*)g,
      (__attribute__((address_space(3))) unsigned int*)lds, 16, 0, 0);
}

// ---------------- converts ----------------

__global__ __launch_bounds__(256) void cvt_kernel(const float* __restrict__ in,
                                                  short* __restrict__ out) {
  int idx = (blockIdx.x * 256 + threadIdx.x) * 4;
  float4 v = *reinterpret_cast<const float4*>(in + idx);
  out[idx + 0] = f2bf(v.x);
  out[idx + 1] = f2bf(v.y);
  out[idx + 2] = f2bf(v.z);
  out[idx + 3] = f2bf(v.w);
}

// W [K=1024][N] fp32 -> W^T [N][1024] bf16, LDS-tiled 64x64 transpose
__global__ __launch_bounds__(256) void cvtT_kernel(const float* __restrict__ in,
                                                   short* __restrict__ out, int N) {
  __shared__ short tile[64][65];
  const int tid = threadIdx.x;
  const int nblk = N >> 6;
  const int nt = blockIdx.x % nblk, kt = blockIdx.x / nblk;
  const int c = tid & 63, r4 = tid >> 6;
#pragma unroll
  for (int r = 0; r < 16; ++r) {
    const int kl = r * 4 + r4;
    tile[kl][c] = f2bf(in[(long)(kt * 64 + kl) * N + nt * 64 + c]);
  }
  __syncthreads();
#pragma unroll
  for (int r = 0; r < 16; ++r) {
    const int nl = r * 4 + r4;
    out[((long)(nt * 64 + nl) << 10) + kt * 64 + c] = tile[c][nl];
  }
}

// ---------------- 256x256 GEMM core, BK=64, 8 waves (2x4), 4-phase pipelined ----------------

DEVI void gemm256_core(const short* __restrict__ A, const short* __restrict__ Bt,
                       int m0, int n0, short (*sA)[16384], short (*sB)[16384],
                       f32x4 (&acc)[8][4]) {
  const int tid = threadIdx.x;
  const int lane = tid & 63, wave = tid >> 6;
  const int wr = wave >> 2, wc = wave & 3;
  const int lr = lane & 15, kg = lane >> 4;

#pragma unroll
  for (int i = 0; i < 8; ++i)
#pragma unroll
    for (int j = 0; j < 4; ++j) {
      f32x4 z = {0.f, 0.f, 0.f, 0.f};
      acc[i][j] = z;
    }

  const int srow = tid >> 3;
  const int scol = ((((tid & 7) << 4)) ^ ((srow & 7) << 4)) >> 1;
  const short* pA = A + (long)(m0 + srow) * 1024 + scol;
  const short* pB = Bt + (long)(n0 + srow) * 1024 + scol;

#pragma unroll
  for (int r = 0; r < 4; ++r) {
    gload_lds16(pA + (long)r * 65536, (char*)sA[0] + r * 8192 + tid * 16);
    gload_lds16(pB + (long)r * 65536, (char*)sB[0] + r * 8192 + tid * 16);
  }
  __syncthreads();

  const int cswz0 = ((kg << 4)) ^ ((lr & 7) << 4);
  const int cswz1 = (64 + (kg << 4)) ^ ((lr & 7) << 4);

  int cur = 0;
  for (int kt = 0; kt < 16; ++kt) {
    const short* sa = sA[cur];
    const short* sb = sB[cur];
    const short* Asrc = pA + (kt + 1) * 64;
    const short* Bsrc = pB + (kt + 1) * 64;
    char* sAn = (char*)sA[cur ^ 1];
    char* sBn = (char*)sB[cur ^ 1];
    const bool notlast = (kt < 15);
    bf16x8 af[4][2], bfr[2][2];

#pragma unroll
    for (int ph = 0; ph < 4; ++ph) {
      const int mh = ph >> 1;
      const int nh = (ph == 1 || ph == 2) ? 1 : 0;
      if (ph == 0 || ph == 2) {
#pragma unroll
        for (int mi = 0; mi < 4; ++mi) {
          const int row = wr * 128 + mh * 64 + mi * 16 + lr;
          af[mi][0] = *(const bf16x8*)((const char*)sa + row * 128 + cswz0);
          af[mi][1] = *(const bf16x8*)((const char*)sa + row * 128 + cswz1);
        }
      }
      if (ph != 2) {
#pragma unroll
        for (int ni = 0; ni < 2; ++ni) {
          const int row = wc * 64 + nh * 32 + ni * 16 + lr;
          bfr[ni][0] = *(const bf16x8*)((const char*)sb + row * 128 + cswz0);
          bfr[ni][1] = *(const bf16x8*)((const char*)sb + row * 128 + cswz1);
        }
      }
      if (notlast) {
        gload_lds16(Asrc + (long)ph * 65536, sAn + ph * 8192 + tid * 16);
        gload_lds16(Bsrc + (long)ph * 65536, sBn + ph * 8192 + tid * 16);
      }
      __builtin_amdgcn_s_barrier();
      __builtin_amdgcn_s_setprio(1);
#pragma unroll
      for (int mi = 0; mi < 4; ++mi)
#pragma unroll
        for (int ni = 0; ni < 2; ++ni) {
          f32x4* a = &acc[mh * 4 + mi][nh * 2 + ni];
          *a = __builtin_amdgcn_mfma_f32_16x16x32_bf16(af[mi][0], bfr[ni][0], *a, 0, 0, 0);
          *a = __builtin_amdgcn_mfma_f32_16x16x32_bf16(af[mi][1], bfr[ni][1], *a, 0, 0, 0);
        }
      __builtin_amdgcn_s_setprio(0);
    }
    if (notlast) __syncthreads();
    cur ^= 1;
  }
}

// ---------------- QKV GEMM ----------------

__global__ __launch_bounds__(512, 2) void qkv_gemm_kernel(const short* __restrict__ xb,
                                                          const short* __restrict__ WaT,
                                                          const float* __restrict__ b_attn,
                                                          short* __restrict__ Qb,
                                                          short* __restrict__ Kb,
                                                          short* __restrict__ Vt) {
  __shared__ short sA[2][16384], sB[2][16384];
  const int bidm = blockIdx.x & 63, bidn = blockIdx.x >> 6;
  const int m0 = bidm << 8, n0 = bidn << 8;
  f32x4 acc[8][4];
  gemm256_core(xb, WaT, m0, n0, sA, sB, acc);

  const int lane = threadIdx.x & 63, wave = threadIdx.x >> 6;
  const int wr = wave >> 2, wc = wave & 3, lr = lane & 15, kg = lane >> 4;
#pragma unroll
  for (int ni = 0; ni < 4; ++ni) {
    const int n = n0 + wc * 64 + ni * 16 + lr;
    const float bias = b_attn[n];
    const int part = n >> 10, c = n & 1023, h = c >> 6, d = c & 63;
#pragma unroll
    for (int mi = 0; mi < 8; ++mi)
#pragma unroll
      for (int r = 0; r < 4; ++r) {
        const int m = m0 + wr * 128 + mi * 16 + kg * 4 + r;
        const int b = m >> 10, t = m & 1023;
        const int bh = b * 16 + h;
        const short bv = f2bf(acc[mi][ni][r] + bias);
        if (part == 0)
          Qb[((long)bh * 1024 + t) * 64 + d] = bv;
        else if (part == 1)
          Kb[((long)bh * 1024 + t) * 64 + d] = bv;
        else
          Vt[((long)bh * 64 + d) * 1024 + t] = bv;
      }
  }
}

// ---------------- flash attention: paired q-tiles, XCD-clustered ----------------
// grid 2048: bh = bid&255, pair j = bid>>8 (0..7); q-tiles j and 15-j -> 17 KV iters/block.
// Same-bh blocks share bid%8 -> same XCD -> K/V L2 reuse.

__global__ __launch_bounds__(256) void attn_kernel(const short* __restrict__ Qb,
                                                   const short* __restrict__ Kb,
                                                   const short* __restrict__ Vt,
                                                   short* __restrict__ Yb) {
  __shared__ short sK[4096], sV[4096];
  __shared__ short sP[4][1024];

  const int bid = blockIdx.x;
  const int bh = bid & 255;
  const int j = bid >> 8;
  const int b = bh >> 4, h = bh & 15;
  const int tid = threadIdx.x, lane = tid & 63, wave = tid >> 6;
  const int lr = lane & 15, lq = lane >> 4;

  const short* Kbh = Kb + (long)bh * 1024 * 64;
  const short* Vbh = Vt + (long)bh * 64 * 1024;
  short* myP = &sP[wave][0];

#pragma unroll
  for (int sel = 0; sel < 2; ++sel) {
    const int qt = sel ? (15 - j) : j;
    const int q0 = qt * 64;

    const short* qrow = Qb + ((long)bh * 1024 + q0 + wave * 16 + lr) * 64;
    bf16x8 qf[2];
    qf[0] = *(const bf16x8*)(qrow + lq * 8);
    qf[1] = *(const bf16x8*)(qrow + 32 + lq * 8);

    f32x4 yacc[4];
#pragma unroll
    for (int i = 0; i < 4; ++i) {
      f32x4 z = {0.f, 0.f, 0.f, 0.f};
      yacc[i] = z;
    }
    float mrow[4], lsum[4];
#pragma unroll
    for (int r = 0; r < 4; ++r) { mrow[r] = -1e30f; lsum[r] = 0.f; }

    for (int kt = 0; kt <= qt; ++kt) {
      gload_lds16(Kbh + ((long)(kt * 64 + (tid & 63))) * 64 + (tid >> 6) * 8, (char*)sK + tid * 16);
      gload_lds16(Kbh + ((long)(kt * 64 + (tid & 63))) * 64 + (4 + (tid >> 6)) * 8, (char*)sK + tid * 16 + 4096);
      gload_lds16(Vbh + (long)(tid & 63) * 1024 + kt * 64 + (tid >> 6) * 8, (char*)sV + tid * 16);
      gload_lds16(Vbh + (long)(tid & 63) * 1024 + kt * 64 + (4 + (tid >> 6)) * 8, (char*)sV + tid * 16 + 4096);
      __syncthreads();

      f32x4 s[4];
#pragma unroll
      for (int i = 0; i < 4; ++i) {
        f32x4 z = {0.f, 0.f, 0.f, 0.f};
        s[i] = z;
      }
      __builtin_amdgcn_s_setprio(1);
#pragma unroll
      for (int kk = 0; kk < 2; ++kk) {
#pragma unroll
        for (int ni = 0; ni < 4; ++ni) {
          bf16x8 kf = *(const bf16x8*)(sK + ((kk * 4 + lq) * 64 + ni * 16 + lr) * 8);
          s[ni] = __builtin_amdgcn_mfma_f32_16x16x32_bf16(qf[kk], kf, s[ni], 0, 0, 0);
        }
      }
      __builtin_amdgcn_s_setprio(0);

      const bool diag = (kt == qt);
#pragma unroll
      for (int ni = 0; ni < 4; ++ni)
#pragma unroll
        for (int r = 0; r < 4; ++r) {
          float v = s[ni][r] * 0.125f;
          if (diag) {
            int tkl = ni * 16 + lr;
            int tql = lq * 4 + r;
            if (tkl > wave * 16 + tql) v = -1e30f;
          }
          s[ni][r] = v;
        }

      float alpha[4], rsum[4];
#pragma unroll
      for (int r = 0; r < 4; ++r) {
        float mx = fmaxf(fmaxf(s[0][r], s[1][r]), fmaxf(s[2][r], s[3][r]));
        mx = fmaxf(mx, __shfl_xor(mx, 1));
        mx = fmaxf(mx, __shfl_xor(mx, 2));
        mx = fmaxf(mx, __shfl_xor(mx, 4));
        mx = fmaxf(mx, __shfl_xor(mx, 8));
        float mnew = fmaxf(mrow[r], mx);
        alpha[r] = __expf(mrow[r] - mnew);
        mrow[r] = mnew;
        rsum[r] = 0.f;
      }

#pragma unroll
      for (int ni = 0; ni < 4; ++ni)
#pragma unroll
        for (int r = 0; r < 4; ++r) {
          float p = __expf(s[ni][r] - mrow[r]);
          rsum[r] += p;
          int row = lq * 4 + r, col = ni * 16 + lr;
          int off = (row * 128 + col * 2) ^ ((row & 7) << 4);
          *(short*)((char*)myP + off) = f2bf(p);
        }
#pragma unroll
      for (int r = 0; r < 4; ++r) {
        float sm = rsum[r];
        sm += __shfl_xor(sm, 1);
        sm += __shfl_xor(sm, 2);
        sm += __shfl_xor(sm, 4);
        sm += __shfl_xor(sm, 8);
        lsum[r] = lsum[r] * alpha[r] + sm;
      }
#pragma unroll
      for (int ni = 0; ni < 4; ++ni)
#pragma unroll
        for (int r = 0; r < 4; ++r) yacc[ni][r] *= alpha[r];

      __builtin_amdgcn_s_setprio(1);
#pragma unroll
      for (int kk = 0; kk < 2; ++kk) {
        int off = (lr * 128 + kk * 64 + lq * 16) ^ ((lr & 7) << 4);
        bf16x8 pf = *(const bf16x8*)((char*)myP + off);
#pragma unroll
        for (int ni = 0; ni < 4; ++ni) {
          bf16x8 vf = *(const bf16x8*)(sV + ((kk * 4 + lq) * 64 + ni * 16 + lr) * 8);
          yacc[ni] = __builtin_amdgcn_mfma_f32_16x16x32_bf16(pf, vf, yacc[ni], 0, 0, 0);
        }
      }
      __builtin_amdgcn_s_setprio(0);
      __syncthreads();
    }

#pragma unroll
    for (int ni = 0; ni < 4; ++ni)
#pragma unroll
      for (int r = 0; r < 4; ++r) {
        int t = q0 + wave * 16 + lq * 4 + r;
        int d = ni * 16 + lr;
        float v = yacc[ni][r] / lsum[r];
        Yb[((long)b * 1024 + t) * 1024 + h * 64 + d] = f2bf(v);
      }
  }
}

// ---------------- output projection GEMM ----------------

__global__ __launch_bounds__(512, 2) void proj_gemm_kernel(const short* __restrict__ Yb,
                                                           const short* __restrict__ WpT,
                                                           const float* __restrict__ b_proj,
                                                           float* __restrict__ out) {
  __shared__ short sA[2][16384], sB[2][16384];
  const int bidm = blockIdx.x & 63, bidn = blockIdx.x >> 6;
  const int m0 = bidm << 8, n0 = bidn << 8;
  f32x4 acc[8][4];
  gemm256_core(Yb, WpT, m0, n0, sA, sB, acc);

  const int lane = threadIdx.x & 63, wave = threadIdx.x >> 6;
  const int wr = wave >> 2, wc = wave & 3, lr = lane & 15, kg = lane >> 4;
#pragma unroll
  for (int ni = 0; ni < 4; ++ni) {
    const int n = n0 + wc * 64 + ni * 16 + lr;
    const float bias = b_proj[n];
#pragma unroll
    for (int mi = 0; mi < 8; ++mi)
#pragma unroll
      for (int r = 0; r < 4; ++r) {
        const int m = m0 + wr * 128 + mi * 16 + kg * 4 + r;
        out[(long)m * 1024 + n] = acc[mi][ni][r] + bias;
      }
  }
}

// ---------------- launcher ----------------

extern "C" void kernel_launch(void* const* d_in, const int* in_sizes, int n_in,
                              void* d_out, int out_size, void* d_ws, size_t ws_size,
                              hipStream_t stream) {
  const float* x = (const float*)d_in[0];
  const float* W_attn = (const float*)d_in[1];
  const float* b_attn = (const float*)d_in[2];
  const float* W_proj = (const float*)d_in[3];
  const float* b_proj = (const float*)d_in[4];
  float* out = (float*)d_out;

  char* ws = (char*)d_ws;
  short* xb = (short*)(ws + 0);
  short* WaT = (short*)(ws + 33554432);
  short* WpT = (short*)(ws + 39845888);
  short* Qb = (short*)(ws + 41943040);
  short* Kb = (short*)(ws + 75497472);
  short* Vt = (short*)(ws + 109051904);
  short* Yb = (short*)(ws + 142606336);

  cvt_kernel<<<16384, 256, 0, stream>>>(x, xb);
  cvtT_kernel<<<768, 256, 0, stream>>>(W_attn, WaT, 3072);
  cvtT_kernel<<<256, 256, 0, stream>>>(W_proj, WpT, 1024);
  qkv_gemm_kernel<<<768, 512, 0, stream>>>(xb, WaT, b_attn, Qb, Kb, Vt);
  attn_kernel<<<2048, 256, 0, stream>>>(Qb, Kb, Vt, Yb);
  proj_gemm_kernel<<<256, 512, 0, stream>>>(Yb, WpT, b_proj, out);
}

// Round 4
// 328.164 us; speedup vs baseline: 1.7121x; 1.1055x over previous
//
#include <hip/hip_runtime.h>
#include <hip/hip_bf16.h>
#include <stdint.h>

#define DEVI __device__ __forceinline__

typedef __attribute__((ext_vector_type(8))) short bf16x8;
typedef __attribute__((ext_vector_type(4))) float f32x4;

DEVI short f2bf(float f) {
  unsigned int u = __builtin_bit_cast(unsigned int, f);
  u = (u + 0x7fffu + ((u >> 16) & 1u)) >> 16;
  return (short)u;
}

DEVI float bf2f(short s) {
  unsigned int u = ((unsigned int)(unsigned short)s) << 16;
  return __builtin_bit_cast(float, u);
}

DEVI void gload_lds16(const void* g, void* lds) {
  __builtin_amdgcn_global_load_lds(
      (const __attribute__((address_space(1))) unsigned int*)g,
      (__attribute__((address_space(3))) unsigned int*)lds, 16, 0, 0);
}

// ---------------- converts ----------------

__global__ __launch_bounds__(256) void cvt_kernel(const float* __restrict__ in,
                                                  short* __restrict__ out) {
  int idx = (blockIdx.x * 256 + threadIdx.x) * 8;
  float4 a = *reinterpret_cast<const float4*>(in + idx);
  float4 b = *reinterpret_cast<const float4*>(in + idx + 4);
  bf16x8 o;
  o[0] = f2bf(a.x); o[1] = f2bf(a.y); o[2] = f2bf(a.z); o[3] = f2bf(a.w);
  o[4] = f2bf(b.x); o[5] = f2bf(b.y); o[6] = f2bf(b.z); o[7] = f2bf(b.w);
  *reinterpret_cast<bf16x8*>(out + idx) = o;
}

// W [K=1024][N] fp32 -> W^T [N][1024] bf16, LDS-tiled 64x64 transpose
__global__ __launch_bounds__(256) void cvtT_kernel(const float* __restrict__ in,
                                                   short* __restrict__ out, int N) {
  __shared__ short tile[64][65];
  const int tid = threadIdx.x;
  const int nblk = N >> 6;
  const int nt = blockIdx.x % nblk, kt = blockIdx.x / nblk;
  const int c = tid & 63, r4 = tid >> 6;
#pragma unroll
  for (int r = 0; r < 16; ++r) {
    const int kl = r * 4 + r4;
    tile[kl][c] = f2bf(in[(long)(kt * 64 + kl) * N + nt * 64 + c]);
  }
  __syncthreads();
#pragma unroll
  for (int r = 0; r < 16; ++r) {
    const int nl = r * 4 + r4;
    out[((long)(nt * 64 + nl) << 10) + kt * 64 + c] = tile[c][nl];
  }
}

// ---------------- 256x256 GEMM core, BK=64, 8 waves (2x4), 4-phase pipelined ----------------
// buffers: sA at sAb + buf*16384, sB at sBb + buf*16384 (shorts)

DEVI void gemm256_core(const short* __restrict__ A, const short* __restrict__ Bt,
                       int m0, int n0, short* sAb, short* sBb, f32x4 (&acc)[8][4]) {
  const int tid = threadIdx.x;
  const int lane = tid & 63, wave = tid >> 6;
  const int wr = wave >> 2, wc = wave & 3;
  const int lr = lane & 15, kg = lane >> 4;

#pragma unroll
  for (int i = 0; i < 8; ++i)
#pragma unroll
    for (int j = 0; j < 4; ++j) {
      f32x4 z = {0.f, 0.f, 0.f, 0.f};
      acc[i][j] = z;
    }

  const int srow = tid >> 3;
  const int scol = ((((tid & 7) << 4)) ^ ((srow & 7) << 4)) >> 1;
  const short* pA = A + (long)(m0 + srow) * 1024 + scol;
  const short* pB = Bt + (long)(n0 + srow) * 1024 + scol;

#pragma unroll
  for (int r = 0; r < 4; ++r) {
    gload_lds16(pA + (long)r * 65536, (char*)sAb + r * 8192 + tid * 16);
    gload_lds16(pB + (long)r * 65536, (char*)sBb + r * 8192 + tid * 16);
  }
  __syncthreads();

  const int cswz0 = ((kg << 4)) ^ ((lr & 7) << 4);
  const int cswz1 = (64 + (kg << 4)) ^ ((lr & 7) << 4);

  int cur = 0;
  for (int kt = 0; kt < 16; ++kt) {
    const short* sa = sAb + cur * 16384;
    const short* sb = sBb + cur * 16384;
    const short* Asrc = pA + (kt + 1) * 64;
    const short* Bsrc = pB + (kt + 1) * 64;
    char* sAn = (char*)(sAb + (cur ^ 1) * 16384);
    char* sBn = (char*)(sBb + (cur ^ 1) * 16384);
    const bool notlast = (kt < 15);
    bf16x8 af[4][2], bfr[2][2];

#pragma unroll
    for (int ph = 0; ph < 4; ++ph) {
      const int mh = ph >> 1;
      const int nh = (ph == 1 || ph == 2) ? 1 : 0;
      if (ph == 0 || ph == 2) {
#pragma unroll
        for (int mi = 0; mi < 4; ++mi) {
          const int row = wr * 128 + mh * 64 + mi * 16 + lr;
          af[mi][0] = *(const bf16x8*)((const char*)sa + row * 128 + cswz0);
          af[mi][1] = *(const bf16x8*)((const char*)sa + row * 128 + cswz1);
        }
      }
      if (ph != 2) {
#pragma unroll
        for (int ni = 0; ni < 2; ++ni) {
          const int row = wc * 64 + nh * 32 + ni * 16 + lr;
          bfr[ni][0] = *(const bf16x8*)((const char*)sb + row * 128 + cswz0);
          bfr[ni][1] = *(const bf16x8*)((const char*)sb + row * 128 + cswz1);
        }
      }
      if (notlast) {
        gload_lds16(Asrc + (long)ph * 65536, sAn + ph * 8192 + tid * 16);
        gload_lds16(Bsrc + (long)ph * 65536, sBn + ph * 8192 + tid * 16);
      }
      __builtin_amdgcn_s_barrier();
      __builtin_amdgcn_s_setprio(1);
#pragma unroll
      for (int mi = 0; mi < 4; ++mi)
#pragma unroll
        for (int ni = 0; ni < 2; ++ni) {
          f32x4* a = &acc[mh * 4 + mi][nh * 2 + ni];
          *a = __builtin_amdgcn_mfma_f32_16x16x32_bf16(af[mi][0], bfr[ni][0], *a, 0, 0, 0);
          *a = __builtin_amdgcn_mfma_f32_16x16x32_bf16(af[mi][1], bfr[ni][1], *a, 0, 0, 0);
        }
      __builtin_amdgcn_s_setprio(0);
    }
    if (notlast) __syncthreads();
    cur ^= 1;
  }
}

// ---------------- QKV GEMM ----------------
// bidn 0-3: Q, 4-7: K (direct coalesced stores); bidn 8-11: V, transposed via LDS.

__global__ __launch_bounds__(512, 2) void qkv_gemm_kernel(const short* __restrict__ xb,
                                                          const short* __restrict__ WaT,
                                                          const float* __restrict__ b_attn,
                                                          short* __restrict__ Qb,
                                                          short* __restrict__ Kb,
                                                          short* __restrict__ Vt) {
  __shared__ short smem[65536];  // 128 KiB: gemm double-buffers, then V-transpose tile
  const int bidm = blockIdx.x & 63, bidn = blockIdx.x >> 6;
  const int m0 = bidm << 8, n0 = bidn << 8;
  f32x4 acc[8][4];
  gemm256_core(xb, WaT, m0, n0, smem, smem + 32768, acc);

  const int tid = threadIdx.x;
  const int lane = tid & 63, wave = tid >> 6;
  const int wr = wave >> 2, wc = wave & 3, lr = lane & 15, kg = lane >> 4;

  if (bidn < 8) {
    // Q or K: [bh][t][64] bf16, 16-lane groups write 32B contiguous
    short* dstbuf = (bidn < 4) ? Qb : Kb;
#pragma unroll
    for (int ni = 0; ni < 4; ++ni) {
      const int n = n0 + wc * 64 + ni * 16 + lr;
      const float bias = b_attn[n];
      const int c = n & 1023, h = c >> 6, d = c & 63;
#pragma unroll
      for (int mi = 0; mi < 8; ++mi)
#pragma unroll
        for (int r = 0; r < 4; ++r) {
          const int m = m0 + wr * 128 + mi * 16 + kg * 4 + r;
          const int b = m >> 10, t = m & 1023;
          const int bh = b * 16 + h;
          dstbuf[((long)bh * 1024 + t) * 64 + d] = f2bf(acc[mi][ni][r] + bias);
        }
    }
  } else {
    // V: transpose through LDS, then coalesced rows of Vt[bh][d][t]
    __syncthreads();  // gemm LDS reads done before overwrite
#pragma unroll
    for (int ni = 0; ni < 4; ++ni) {
      const int nl = wc * 64 + ni * 16 + lr;
      const float bias = b_attn[n0 + nl];
      const int swz = (nl & 7) << 3;
#pragma unroll
      for (int mi = 0; mi < 8; ++mi)
#pragma unroll
        for (int r = 0; r < 4; ++r) {
          const int ml = wr * 128 + mi * 16 + kg * 4 + r;
          smem[nl * 256 + (ml ^ swz)] = f2bf(acc[mi][ni][r] + bias);
        }
    }
    __syncthreads();
    const int row = tid >> 1, mh = tid & 1;          // row = n_local, mh = m-half
    const int c = ((n0 & 1023) + row);
    const int h = c >> 6, d = c & 63;
    const int mstart = mh * 128;
    const long mg = m0 + mstart;
    const int b = (int)(mg >> 10), t0 = (int)(mg & 1023);
    short* dst = Vt + ((long)(b * 16 + h) * 64 + d) * 1024 + t0;
    const int swz = (row & 7) << 3;
#pragma unroll
    for (int g = 0; g < 16; ++g) {
      bf16x8 v = *(const bf16x8*)&smem[row * 256 + ((mstart + g * 8) ^ swz)];
      *(bf16x8*)(dst + g * 8) = v;
    }
  }
}

// ---------------- flash attention: paired q-tiles, XCD-clustered, K/V double-buffered ----------------

__global__ __launch_bounds__(256) void attn_kernel(const short* __restrict__ Qb,
                                                   const short* __restrict__ Kb,
                                                   const short* __restrict__ Vt,
                                                   short* __restrict__ Yb) {
  __shared__ short sK[2][4096], sV[2][4096];
  __shared__ short sP[4][1024];

  const int bid = blockIdx.x;
  const int bh = bid & 255;
  const int j = bid >> 8;
  const int b = bh >> 4, h = bh & 15;
  const int tid = threadIdx.x, lane = tid & 63, wave = tid >> 6;
  const int lr = lane & 15, lq = lane >> 4;
  const int tkr = tid & 63, tkg = tid >> 6;

  const short* Kbh = Kb + (long)bh * 1024 * 64;
  const short* Vbh = Vt + (long)bh * 64 * 1024;
  short* myP = &sP[wave][0];

#define STAGE_KV(kt_, bi_)                                                                        \
  do {                                                                                            \
    gload_lds16(Kbh + ((long)((kt_) * 64 + tkr)) * 64 + tkg * 8, (char*)sK[bi_] + tid * 16);      \
    gload_lds16(Kbh + ((long)((kt_) * 64 + tkr)) * 64 + (4 + tkg) * 8,                            \
                (char*)sK[bi_] + tid * 16 + 4096);                                                \
    gload_lds16(Vbh + (long)tkr * 1024 + (kt_) * 64 + tkg * 8, (char*)sV[bi_] + tid * 16);        \
    gload_lds16(Vbh + (long)tkr * 1024 + (kt_) * 64 + (4 + tkg) * 8,                              \
                (char*)sV[bi_] + tid * 16 + 4096);                                                \
  } while (0)

#pragma unroll
  for (int sel = 0; sel < 2; ++sel) {
    const int qt = sel ? (15 - j) : j;
    const int q0 = qt * 64;

    // Q fragments, pre-scaled by 1/8 (exact in bf16)
    const short* qrow = Qb + ((long)bh * 1024 + q0 + wave * 16 + lr) * 64;
    bf16x8 qr0 = *(const bf16x8*)(qrow + lq * 8);
    bf16x8 qr1 = *(const bf16x8*)(qrow + 32 + lq * 8);
    bf16x8 qf[2];
#pragma unroll
    for (int e = 0; e < 8; ++e) {
      qf[0][e] = f2bf(bf2f(qr0[e]) * 0.125f);
      qf[1][e] = f2bf(bf2f(qr1[e]) * 0.125f);
    }

    f32x4 yacc[4];
#pragma unroll
    for (int i = 0; i < 4; ++i) {
      f32x4 z = {0.f, 0.f, 0.f, 0.f};
      yacc[i] = z;
    }
    float mrow[4], lsum[4];
#pragma unroll
    for (int r = 0; r < 4; ++r) { mrow[r] = -1e30f; lsum[r] = 0.f; }

    STAGE_KV(0, 0);
    __syncthreads();
    int cur = 0;

    for (int kt = 0; kt <= qt; ++kt) {
      if (kt < qt) STAGE_KV(kt + 1, cur ^ 1);  // in flight under compute

      const short* sk = sK[cur];
      const short* sv = sV[cur];

      f32x4 s[4];
#pragma unroll
      for (int i = 0; i < 4; ++i) {
        f32x4 z = {0.f, 0.f, 0.f, 0.f};
        s[i] = z;
      }
      __builtin_amdgcn_s_setprio(1);
#pragma unroll
      for (int kk = 0; kk < 2; ++kk) {
#pragma unroll
        for (int ni = 0; ni < 4; ++ni) {
          bf16x8 kf = *(const bf16x8*)(sk + ((kk * 4 + lq) * 64 + ni * 16 + lr) * 8);
          s[ni] = __builtin_amdgcn_mfma_f32_16x16x32_bf16(qf[kk], kf, s[ni], 0, 0, 0);
        }
      }
      __builtin_amdgcn_s_setprio(0);

      if (kt == qt) {
#pragma unroll
        for (int ni = 0; ni < 4; ++ni)
#pragma unroll
          for (int r = 0; r < 4; ++r) {
            int tkl = ni * 16 + lr;
            int tql = lq * 4 + r;
            if (tkl > wave * 16 + tql) s[ni][r] = -1e30f;
          }
      }

      float alpha[4], rsum[4];
#pragma unroll
      for (int r = 0; r < 4; ++r) {
        float mx = fmaxf(fmaxf(s[0][r], s[1][r]), fmaxf(s[2][r], s[3][r]));
        mx = fmaxf(mx, __shfl_xor(mx, 1));
        mx = fmaxf(mx, __shfl_xor(mx, 2));
        mx = fmaxf(mx, __shfl_xor(mx, 4));
        mx = fmaxf(mx, __shfl_xor(mx, 8));
        float mnew = fmaxf(mrow[r], mx);
        alpha[r] = __expf(mrow[r] - mnew);
        mrow[r] = mnew;
        rsum[r] = 0.f;
      }

#pragma unroll
      for (int ni = 0; ni < 4; ++ni)
#pragma unroll
        for (int r = 0; r < 4; ++r) {
          float p = __expf(s[ni][r] - mrow[r]);
          rsum[r] += p;
          int row = lq * 4 + r, col = ni * 16 + lr;
          int off = (row * 128 + col * 2) ^ ((row & 7) << 4);
          *(short*)((char*)myP + off) = f2bf(p);
        }
#pragma unroll
      for (int r = 0; r < 4; ++r) {
        float sm = rsum[r];
        sm += __shfl_xor(sm, 1);
        sm += __shfl_xor(sm, 2);
        sm += __shfl_xor(sm, 4);
        sm += __shfl_xor(sm, 8);
        lsum[r] = lsum[r] * alpha[r] + sm;
      }
#pragma unroll
      for (int ni = 0; ni < 4; ++ni)
#pragma unroll
        for (int r = 0; r < 4; ++r) yacc[ni][r] *= alpha[r];

      __builtin_amdgcn_s_setprio(1);
#pragma unroll
      for (int kk = 0; kk < 2; ++kk) {
        int off = (lr * 128 + kk * 64 + lq * 16) ^ ((lr & 7) << 4);
        bf16x8 pf = *(const bf16x8*)((char*)myP + off);
#pragma unroll
        for (int ni = 0; ni < 4; ++ni) {
          bf16x8 vf = *(const bf16x8*)(sv + ((kk * 4 + lq) * 64 + ni * 16 + lr) * 8);
          yacc[ni] = __builtin_amdgcn_mfma_f32_16x16x32_bf16(pf, vf, yacc[ni], 0, 0, 0);
        }
      }
      __builtin_amdgcn_s_setprio(0);
      __syncthreads();  // drains staged loads; next tile ready, P/buffers reusable
      cur ^= 1;
    }

#pragma unroll
    for (int ni = 0; ni < 4; ++ni)
#pragma unroll
      for (int r = 0; r < 4; ++r) {
        int t = q0 + wave * 16 + lq * 4 + r;
        int d = ni * 16 + lr;
        float v = yacc[ni][r] / lsum[r];
        Yb[((long)b * 1024 + t) * 1024 + h * 64 + d] = f2bf(v);
      }
  }
#undef STAGE_KV
}

// ---------------- output projection GEMM ----------------

__global__ __launch_bounds__(512, 2) void proj_gemm_kernel(const short* __restrict__ Yb,
                                                           const short* __restrict__ WpT,
                                                           const float* __restrict__ b_proj,
                                                           float* __restrict__ out) {
  __shared__ short smem[65536];
  const int bidm = blockIdx.x & 63, bidn = blockIdx.x >> 6;
  const int m0 = bidm << 8, n0 = bidn << 8;
  f32x4 acc[8][4];
  gemm256_core(Yb, WpT, m0, n0, smem, smem + 32768, acc);

  const int lane = threadIdx.x & 63, wave = threadIdx.x >> 6;
  const int wr = wave >> 2, wc = wave & 3, lr = lane & 15, kg = lane >> 4;
#pragma unroll
  for (int ni = 0; ni < 4; ++ni) {
    const int n = n0 + wc * 64 + ni * 16 + lr;
    const float bias = b_proj[n];
#pragma unroll
    for (int mi = 0; mi < 8; ++mi)
#pragma unroll
      for (int r = 0; r < 4; ++r) {
        const int m = m0 + wr * 128 + mi * 16 + kg * 4 + r;
        out[(long)m * 1024 + n] = acc[mi][ni][r] + bias;
      }
  }
}

// ---------------- launcher ----------------

extern "C" void kernel_launch(void* const* d_in, const int* in_sizes, int n_in,
                              void* d_out, int out_size, void* d_ws, size_t ws_size,
                              hipStream_t stream) {
  const float* x = (const float*)d_in[0];
  const float* W_attn = (const float*)d_in[1];
  const float* b_attn = (const float*)d_in[2];
  const float* W_proj = (const float*)d_in[3];
  const float* b_proj = (const float*)d_in[4];
  float* out = (float*)d_out;

  char* ws = (char*)d_ws;
  short* xb = (short*)(ws + 0);
  short* WaT = (short*)(ws + 33554432);
  short* WpT = (short*)(ws + 39845888);
  short* Qb = (short*)(ws + 41943040);
  short* Kb = (short*)(ws + 75497472);
  short* Vt = (short*)(ws + 109051904);
  short* Yb = (short*)(ws + 142606336);

  cvt_kernel<<<8192, 256, 0, stream>>>(x, xb);
  cvtT_kernel<<<768, 256, 0, stream>>>(W_attn, WaT, 3072);
  cvtT_kernel<<<256, 256, 0, stream>>>(W_proj, WpT, 1024);
  qkv_gemm_kernel<<<768, 512, 0, stream>>>(xb, WaT, b_attn, Qb, Kb, Vt);
  attn_kernel<<<2048, 256, 0, stream>>>(Qb, Kb, Vt, Yb);
  proj_gemm_kernel<<<256, 512, 0, stream>>>(Yb, WpT, b_proj, out);
}